// Round 21
// baseline (102.219 us; speedup 1.0000x reference)
//
#include <hip/hip_runtime.h>

#define N_ROWS 131072
#define DIM 64
#define KCODES 512
#define MARGIN 1e-4f
#define QCAP 32768

typedef __attribute__((ext_vector_type(8))) short bf16x8;
typedef __attribute__((ext_vector_type(4))) float f32x4;

// ws layout (4-byte words):
// [0..256)        lossp f32[256]           (zeroed by wprep)
// [256..4352)     hist8 u32[8][512]        (zeroed by wprep)
// [4352]          qcount u32               (zeroed by wprep)
// [4353..4360)    pad
// [4360..37128)   queue u32[QCAP]
// [37128..37640)  bnp f32[512]
// [37640..70408)  wfrag ushort[65536] B-fragment image (hi+lo):
//                 frag = cti*256 + q*64 + lane (16B units); q:0=hi k0,1=hi k1,2=lo k0,3=lo k1

__device__ __forceinline__ float sqr_nf(float x) {
    float s = x * x;
    asm("" : "+v"(s));   // numpy rounds the square before summing
    return s;
}

__device__ __forceinline__ unsigned short f2bf(float f) {  // RNE, finite data
    unsigned u = __float_as_uint(f);
    u += 0x7fffu + ((u >> 16) & 1u);
    return (unsigned short)(u >> 16);
}
__device__ __forceinline__ float bf2f(unsigned short b) {
    return __uint_as_float(((unsigned)b) << 16);
}

__device__ __forceinline__ void cvtpair(float4 a, float4 b, bf16x8& hi, bf16x8& lo) {
    float v[8] = {a.x, a.y, a.z, a.w, b.x, b.y, b.z, b.w};
#pragma unroll
    for (int j = 0; j < 8; ++j) {
        unsigned short h = f2bf(v[j]);
        hi[j] = (short)h;
        lo[j] = (short)f2bf(v[j] - bf2f(h));
    }
}
__device__ __forceinline__ float4 scl(float4 v, float s) {
    return make_float4(v.x * s, v.y * s, v.z * s, v.w * s);
}

// ---- precompute: ws zero + W -> bf16 hi/lo B-fragment image + np norms -----
__global__ __launch_bounds__(256) void vq_wprep_k(
    const float* __restrict__ W, unsigned* __restrict__ ws_zero,
    unsigned short* __restrict__ wfrag, float* __restrict__ bnp) {
    int code = blockIdx.x * 256 + threadIdx.x;   // 0..511
    for (int i = code; i < 4353; i += 512) ws_zero[i] = 0u;

    float p[64];
#pragma unroll
    for (int i = 0; i < 16; ++i) {
        float4 v = reinterpret_cast<const float4*>(W)[code * 16 + i];
        p[i * 4 + 0] = v.x; p[i * 4 + 1] = v.y;
        p[i * 4 + 2] = v.z; p[i * 4 + 3] = v.w;
    }
    unsigned short hi[64], lo[64];
#pragma unroll
    for (int d = 0; d < 64; ++d) {
        hi[d] = f2bf(p[d]);
        lo[d] = f2bf(p[d] - bf2f(hi[d]));
    }
    {   // np pairwise codeword norm  [validated rounds 3-20, absmax 0]
        float r[8];
#pragma unroll
        for (int j = 0; j < 8; ++j) r[j] = sqr_nf(p[j]);
#pragma unroll
        for (int i = 1; i < 8; ++i)
#pragma unroll
            for (int j = 0; j < 8; ++j) r[j] += sqr_nf(p[i * 8 + j]);
        bnp[code] = ((r[0] + r[1]) + (r[2] + r[3])) + ((r[4] + r[5]) + (r[6] + r[7]));
    }
    const int cti = code >> 4, m = code & 15;
#pragma unroll
    for (int part = 0; part < 2; ++part) {
        const unsigned short* src = part ? lo : hi;
#pragma unroll
        for (int s = 0; s < 2; ++s) {
            int q = part * 2 + s;
#pragma unroll
            for (int kq = 0; kq < 4; ++kq) {
                int lane = kq * 16 + m;
                size_t off = ((size_t)(cti * 4 + q) * 64 + lane) * 8;
                *reinterpret_cast<uint4*>(wfrag + off) =
                    *reinterpret_cast<const uint4*>(src + s * 32 + kq * 8);
            }
        }
    }
}

// fold helper for one cti's pair of accumulators
#define FOLD_STEP(KK, C0, C1)                                                 \
    {                                                                         \
        _Pragma("unroll")                                                     \
        for (int rt = 0; rt < 2; ++rt)                                        \
            _Pragma("unroll")                                                 \
            for (int j = 0; j < 4; ++j) {                                     \
                float s = (rt == 0) ? (C0)[j] : (C1)[j];                      \
                float nb = fminf(best[rt][j], s);                             \
                float ns = fminf(sec[rt][j], fmaxf(best[rt][j], s));          \
                bidx[rt][j] = (s < best[rt][j]) ? (KK) : bidx[rt][j];         \
                best[rt][j] = nb; sec[rt][j] = ns;                            \
            }                                                                 \
    }

// ---- fused main: paired-cti scoring (4 indep chains) + in-wave epilogue ----
__global__ __launch_bounds__(256, 3) void vq_main_k(
    const float* __restrict__ X, const float* __restrict__ Wf,
    const unsigned short* __restrict__ wfrag, const float* __restrict__ bnp,
    float* __restrict__ out_q, float* __restrict__ out_idx,
    unsigned* __restrict__ hist8, float* __restrict__ lossp,
    unsigned* __restrict__ qcount, unsigned* __restrict__ queue) {
    __shared__ int idx_s[128];
    const int tid = threadIdx.x;
    const int lane = tid & 63, w = tid >> 6;
    const int m = lane & 15, kq = lane >> 4;
    const long rbase = (long)blockIdx.x * 128;
    const unsigned hstripe = (blockIdx.x & 7) * KCODES;

    bf16x8 ahi[2][2], alo[2][2];
#pragma unroll
    for (int rt = 0; rt < 2; ++rt) {
        long row = rbase + w * 32 + rt * 16 + m;
        const float4* xp = reinterpret_cast<const float4*>(X + row * DIM);
        cvtpair(scl(xp[kq * 2], -2.f), scl(xp[kq * 2 + 1], -2.f),
                ahi[rt][0], alo[rt][0]);
        cvtpair(scl(xp[8 + kq * 2], -2.f), scl(xp[8 + kq * 2 + 1], -2.f),
                ahi[rt][1], alo[rt][1]);
    }

    float best[2][4], sec[2][4];
    int bidx[2][4];
#pragma unroll
    for (int rt = 0; rt < 2; ++rt)
#pragma unroll
        for (int j = 0; j < 4; ++j) { best[rt][j] = 3e38f; sec[rt][j] = 3e38f; bidx[rt][j] = 0; }

    const bf16x8* fb = reinterpret_cast<const bf16x8*>(wfrag);
    // 1-pair-deep prefetch, NAMED registers (r15 lesson: no runtime-indexed arrays)
    bf16x8 pa0 = fb[lane], pa1 = fb[64 + lane], pa2 = fb[128 + lane], pa3 = fb[192 + lane];
    bf16x8 pb0 = fb[256 + lane], pb1 = fb[320 + lane], pb2 = fb[384 + lane], pb3 = fb[448 + lane];

    for (int cti = 0; cti < 32; cti += 2) {
        bf16x8 b0 = pa0, b1 = pa1, b2 = pa2, b3 = pa3;
        bf16x8 b4 = pb0, b5 = pb1, b6 = pb2, b7 = pb3;
        if (cti + 2 < 32) {
            int na = (cti + 2) * 256, nb = (cti + 3) * 256;
            pa0 = fb[na + lane];       pa1 = fb[na + 64 + lane];
            pa2 = fb[na + 128 + lane]; pa3 = fb[na + 192 + lane];
            pb0 = fb[nb + lane];       pb1 = fb[nb + 64 + lane];
            pb2 = fb[nb + 128 + lane]; pb3 = fb[nb + 192 + lane];
        }
        const int kkA = cti * 16 + m, kkB = (cti + 1) * 16 + m;
        const float wnA = bnp[kkA], wnB = bnp[kkB];
        // 4 INDEPENDENT 6-deep chains, issued round-robin (c: cti, d: cti+1)
        f32x4 c0 = {wnA, wnA, wnA, wnA}, c1 = {wnA, wnA, wnA, wnA};
        f32x4 d0 = {wnB, wnB, wnB, wnB}, d1 = {wnB, wnB, wnB, wnB};
        c0 = __builtin_amdgcn_mfma_f32_16x16x32_bf16(ahi[0][0], b0, c0, 0, 0, 0);
        c1 = __builtin_amdgcn_mfma_f32_16x16x32_bf16(ahi[1][0], b0, c1, 0, 0, 0);
        d0 = __builtin_amdgcn_mfma_f32_16x16x32_bf16(ahi[0][0], b4, d0, 0, 0, 0);
        d1 = __builtin_amdgcn_mfma_f32_16x16x32_bf16(ahi[1][0], b4, d1, 0, 0, 0);
        c0 = __builtin_amdgcn_mfma_f32_16x16x32_bf16(ahi[0][1], b1, c0, 0, 0, 0);
        c1 = __builtin_amdgcn_mfma_f32_16x16x32_bf16(ahi[1][1], b1, c1, 0, 0, 0);
        d0 = __builtin_amdgcn_mfma_f32_16x16x32_bf16(ahi[0][1], b5, d0, 0, 0, 0);
        d1 = __builtin_amdgcn_mfma_f32_16x16x32_bf16(ahi[1][1], b5, d1, 0, 0, 0);
        c0 = __builtin_amdgcn_mfma_f32_16x16x32_bf16(alo[0][0], b0, c0, 0, 0, 0);
        c1 = __builtin_amdgcn_mfma_f32_16x16x32_bf16(alo[1][0], b0, c1, 0, 0, 0);
        d0 = __builtin_amdgcn_mfma_f32_16x16x32_bf16(alo[0][0], b4, d0, 0, 0, 0);
        d1 = __builtin_amdgcn_mfma_f32_16x16x32_bf16(alo[1][0], b4, d1, 0, 0, 0);
        c0 = __builtin_amdgcn_mfma_f32_16x16x32_bf16(alo[0][1], b1, c0, 0, 0, 0);
        c1 = __builtin_amdgcn_mfma_f32_16x16x32_bf16(alo[1][1], b1, c1, 0, 0, 0);
        d0 = __builtin_amdgcn_mfma_f32_16x16x32_bf16(alo[0][1], b5, d0, 0, 0, 0);
        d1 = __builtin_amdgcn_mfma_f32_16x16x32_bf16(alo[1][1], b5, d1, 0, 0, 0);
        c0 = __builtin_amdgcn_mfma_f32_16x16x32_bf16(ahi[0][0], b2, c0, 0, 0, 0);
        c1 = __builtin_amdgcn_mfma_f32_16x16x32_bf16(ahi[1][0], b2, c1, 0, 0, 0);
        d0 = __builtin_amdgcn_mfma_f32_16x16x32_bf16(ahi[0][0], b6, d0, 0, 0, 0);
        d1 = __builtin_amdgcn_mfma_f32_16x16x32_bf16(ahi[1][0], b6, d1, 0, 0, 0);
        c0 = __builtin_amdgcn_mfma_f32_16x16x32_bf16(ahi[0][1], b3, c0, 0, 0, 0);
        c1 = __builtin_amdgcn_mfma_f32_16x16x32_bf16(ahi[1][1], b3, c1, 0, 0, 0);
        d0 = __builtin_amdgcn_mfma_f32_16x16x32_bf16(ahi[0][1], b7, d0, 0, 0, 0);
        d1 = __builtin_amdgcn_mfma_f32_16x16x32_bf16(ahi[1][1], b7, d1, 0, 0, 0);
        FOLD_STEP(kkA, c0, c1);
        FOLD_STEP(kkB, d0, d1);
    }

    // merge across the 16 m-lanes; exact ties -> smaller index
#pragma unroll
    for (int st = 1; st < 16; st <<= 1) {
#pragma unroll
        for (int rt = 0; rt < 2; ++rt)
#pragma unroll
            for (int j = 0; j < 4; ++j) {
                float ob = __shfl_xor(best[rt][j], st);
                float os = __shfl_xor(sec[rt][j], st);
                int oi = __shfl_xor(bidx[rt][j], st);
                if (ob < best[rt][j] || (ob == best[rt][j] && oi < bidx[rt][j])) {
                    sec[rt][j] = fminf(best[rt][j], os);
                    best[rt][j] = ob; bidx[rt][j] = oi;
                } else {
                    sec[rt][j] = fminf(sec[rt][j], ob);
                }
            }
    }

    if (m == 0) {   // C/D row = kq*4 + j; publish to LDS + out_idx
#pragma unroll
        for (int rt = 0; rt < 2; ++rt)
#pragma unroll
            for (int j = 0; j < 4; ++j) {
                int r = w * 32 + rt * 16 + kq * 4 + j;
                int id = (sec[rt][j] - best[rt][j] <= MARGIN) ? -1 : bidx[rt][j];
                idx_s[r] = id;
                out_idx[rbase + r] = (float)id;   // sentinel -> refine overwrites
            }
    }
    // same-wave LDS write->read: ordered by program order + lgkmcnt (no barrier)

    // ---- fused epilogue (batched 8-deep-ILP body, per wave) ----------------
    const int g = lane >> 4, l16 = lane & 15;
    const long wbase = rbase + w * 32;
    int idxi = (lane < 32) ? idx_s[w * 32 + lane] : 0;

    if (lane < 32 && idxi < 0) {
        unsigned pos = atomicAdd(qcount, 1u);
        if (pos < QCAP) queue[pos] = (unsigned)(wbase + lane);
    }

    float4 xv[8], wv[8];
    int kk2[8];
#pragma unroll
    for (int i = 0; i < 8; ++i) {
        int r2 = g * 8 + i;
        int kf = __shfl(idxi, r2);
        kk2[i] = kf;
        xv[i] = reinterpret_cast<const float4*>(X)[(wbase + r2) * 16 + l16];
        int ksafe = (kf >= 0) ? kf : 0;
        wv[i] = reinterpret_cast<const float4*>(Wf)[(long)ksafe * 16 + l16];
    }

    float ls = 0.f;
#pragma unroll
    for (int i = 0; i < 8; ++i) {
        if (kk2[i] >= 0) {
            float4 o; float t;
            t = wv[i].x - xv[i].x; o.x = xv[i].x + t; ls = fmaf(t, t, ls);
            t = wv[i].y - xv[i].y; o.y = xv[i].y + t; ls = fmaf(t, t, ls);
            t = wv[i].z - xv[i].z; o.z = xv[i].z + t; ls = fmaf(t, t, ls);
            t = wv[i].w - xv[i].w; o.w = xv[i].w + t; ls = fmaf(t, t, ls);
            reinterpret_cast<float4*>(out_q)[(wbase + g * 8 + i) * 16 + l16] = o;
            if (l16 == 0) atomicAdd(&hist8[hstripe + kk2[i]], 1u);
        }
    }

#pragma unroll
    for (int st = 1; st < 64; st <<= 1) ls += __shfl_xor(ls, st);
    if (lane == 0 && ls != 0.f) atomicAdd(&lossp[blockIdx.x & 255], ls);
}

// ---- refine: load-balanced np-exact, W^T in LDS; grid 128 ------------------
#define WTP 516
__global__ __launch_bounds__(1024) void vq_refine_k(
    const float* __restrict__ X, const float* __restrict__ Wf,
    const float* __restrict__ bnp,
    float* __restrict__ out_q, float* __restrict__ out_idx,
    unsigned* __restrict__ hist8, float* __restrict__ lossp,
    const unsigned* __restrict__ qcount, const unsigned* __restrict__ queue) {
    __shared__ float WT[64 * WTP];   // WT[d][k] = W[k][d], 132KB
    const int tid = threadIdx.x;
    const int lane = tid & 63, wv = tid >> 6;

#pragma unroll
    for (int i = 0; i < 8; ++i) {
        int f = i * 1024 + tid;
        int k = f >> 4, c4 = f & 15;
        float4 v = reinterpret_cast<const float4*>(Wf)[f];
        WT[(c4 * 4 + 0) * WTP + k] = v.x;
        WT[(c4 * 4 + 1) * WTP + k] = v.y;
        WT[(c4 * 4 + 2) * WTP + k] = v.z;
        WT[(c4 * 4 + 3) * WTP + k] = v.w;
    }
    __syncthreads();

    unsigned n = *qcount;
    if (n > QCAP) n = QCAP;
    const int gwave = blockIdx.x * 16 + wv;

    float ls = 0.f;
    for (unsigned j = gwave; j < n; j += 128 * 16) {
        const long row = (long)queue[j];
        const float xv = X[row * DIM + lane];
        float sq = sqr_nf(xv);
        float rr = sq;
#pragma unroll
        for (int t2 = 1; t2 < 8; ++t2) rr += __shfl(sq, (lane & 7) + 8 * t2);
        float t01 = rr + __shfl_xor(rr, 1);
        float t03 = t01 + __shfl_xor(t01, 2);
        float Afull = t03 + __shfl_xor(t03, 4);
        const float A = __shfl(Afull, 0);
        float acc[8];
#pragma unroll
        for (int c = 0; c < 8; ++c) acc[c] = 0.f;
        for (int d = 0; d < 64; ++d) {
            float xd = __shfl(xv, d);
#pragma unroll
            for (int c = 0; c < 8; ++c)
                acc[c] = fmaf(xd, WT[d * WTP + c * 64 + lane], acc[c]);
        }
        float bs = 3e38f;
        int bi = 0;
#pragma unroll
        for (int c = 0; c < 8; ++c) {
            int k = c * 64 + lane;
            float u = A + bnp[k];
            float s2 = u - 2.0f * acc[c];
            if (s2 < bs) { bs = s2; bi = k; }
        }
#pragma unroll
        for (int st = 1; st < 64; st <<= 1) {
            float ob = __shfl_xor(bs, st);
            int oi = __shfl_xor(bi, st);
            if (ob < bs || (ob == bs && oi < bi)) { bs = ob; bi = oi; }
        }
        const int k = bi;
        if (lane == 0) {
            out_idx[row] = (float)k;
            atomicAdd(&hist8[(j & 7) * KCODES + k], 1u);
        }
        float qv = WT[lane * WTP + k];
        float diff = qv - xv;
        out_q[row * DIM + lane] = xv + diff;
        ls = fmaf(diff, diff, ls);
    }

#pragma unroll
    for (int st = 1; st < 64; st <<= 1) ls += __shfl_xor(ls, st);
    if (lane == 0 && ls != 0.f) atomicAdd(&lossp[gwave & 255], ls);
}

__global__ __launch_bounds__(512) void vq_finalize_k(
    const unsigned* __restrict__ hist8, const float* __restrict__ lossp,
    float* __restrict__ out_loss, float* __restrict__ out_perp) {
    __shared__ float red[512];
    int t = threadIdx.x;
    unsigned c = 0;
#pragma unroll
    for (int s = 0; s < 8; ++s) c += hist8[s * KCODES + t];
    float p = (float)c * (1.0f / (float)N_ROWS);
    red[t] = p * logf(p + 1e-10f);
    __syncthreads();
    for (int off = 256; off; off >>= 1) {
        if (t < off) red[t] += red[t + off];
        __syncthreads();
    }
    if (t == 0) *out_perp = expf(-red[0]);
    __syncthreads();
    red[t] = (t < 256) ? lossp[t] : 0.f;
    __syncthreads();
    for (int off = 256; off; off >>= 1) {
        if (t < off) red[t] += red[t + off];
        __syncthreads();
    }
    if (t == 0) {
        float m = red[0] / (float)(N_ROWS * DIM);
        *out_loss = m + 0.25f * m;
    }
}

extern "C" void kernel_launch(void* const* d_in, const int* in_sizes, int n_in,
                              void* d_out, int out_size, void* d_ws, size_t ws_size,
                              hipStream_t stream) {
    const float* X = (const float*)d_in[0];
    const float* Wf = (const float*)d_in[1];

    float* out = (float*)d_out;
    float* out_loss = out;
    float* out_q = out + 1;
    float* out_perp = out + 1 + (long)N_ROWS * DIM;
    float* out_idx = out + 2 + (long)N_ROWS * DIM;

    unsigned* wsu = (unsigned*)d_ws;
    float* lossp = (float*)d_ws;                    // [0..256)
    unsigned* hist8 = wsu + 256;                    // [256..4352)
    unsigned* qcount = wsu + 4352;                  // [4352]
    unsigned* queue = wsu + 4360;                   // [4360..37128)
    float* bnp = (float*)(wsu + 37128);             // [37128..37640)
    unsigned short* wfrag = (unsigned short*)(wsu + 37640);  // [37640..70408)

    vq_wprep_k<<<2, 256, 0, stream>>>(Wf, wsu, wfrag, bnp);
    vq_main_k<<<N_ROWS / 128, 256, 0, stream>>>(X, Wf, wfrag, bnp,
                                                out_q, out_idx,
                                                hist8, lossp, qcount, queue);
    vq_refine_k<<<128, 1024, 0, stream>>>(X, Wf, bnp, out_q, out_idx,
                                          hist8, lossp, qcount, queue);
    vq_finalize_k<<<1, 512, 0, stream>>>(hist8, lossp, out_loss, out_perp);
}

// Round 22
// 94.556 us; speedup vs baseline: 1.0810x; 1.0810x over previous
//
#include <hip/hip_runtime.h>

#define N_ROWS 131072
#define DIM 64
#define KCODES 512
#define MARGIN 1e-4f
#define QCAP 32768

typedef __attribute__((ext_vector_type(8))) short bf16x8;
typedef __attribute__((ext_vector_type(4))) float f32x4;

// ws layout (4-byte words):
// [0..256)        lossp f32[256]           (zeroed)
// [256..4352)     hist8 u32[8][512]        (zeroed)
// [4352]          qcount u32               (zeroed)
// [4353..4360)    pad
// [4360..37128)   queue u32[QCAP]
// [37128..37640)  bnp f32[512]
// [37640..70408)  wfrag ushort[65536] B-fragment image:
//                 frag = cti*256 + q*64 + lane (16B units); q:0=hi k0,1=hi k1,2=lo k0,3=lo k1

__device__ __forceinline__ float sqr_nf(float x) {
    float s = x * x;
    asm("" : "+v"(s));   // numpy rounds the square before summing
    return s;
}

__device__ __forceinline__ unsigned short f2bf(float f) {  // RNE, finite data
    unsigned u = __float_as_uint(f);
    u += 0x7fffu + ((u >> 16) & 1u);
    return (unsigned short)(u >> 16);
}
__device__ __forceinline__ float bf2f(unsigned short b) {
    return __uint_as_float(((unsigned)b) << 16);
}

__device__ __forceinline__ void cvtpair(float4 a, float4 b, bf16x8& hi, bf16x8& lo) {
    float v[8] = {a.x, a.y, a.z, a.w, b.x, b.y, b.z, b.w};
#pragma unroll
    for (int j = 0; j < 8; ++j) {
        unsigned short h = f2bf(v[j]);
        hi[j] = (short)h;
        lo[j] = (short)f2bf(v[j] - bf2f(h));
    }
}
__device__ __forceinline__ float4 scl(float4 v, float s) {
    return make_float4(v.x * s, v.y * s, v.z * s, v.w * s);
}

// ---- precompute: W -> bf16 hi/lo B-fragment image + np-exact norms ---------
__global__ __launch_bounds__(256) void vq_wprep_k(
    const float* __restrict__ W, unsigned short* __restrict__ wfrag,
    float* __restrict__ bnp) {
    int code = blockIdx.x * 256 + threadIdx.x;   // 0..511
    float p[64];
#pragma unroll
    for (int i = 0; i < 16; ++i) {
        float4 v = reinterpret_cast<const float4*>(W)[code * 16 + i];
        p[i * 4 + 0] = v.x; p[i * 4 + 1] = v.y;
        p[i * 4 + 2] = v.z; p[i * 4 + 3] = v.w;
    }
    unsigned short hi[64], lo[64];
#pragma unroll
    for (int d = 0; d < 64; ++d) {
        hi[d] = f2bf(p[d]);
        lo[d] = f2bf(p[d] - bf2f(hi[d]));
    }
    {   // np pairwise codeword norm  [validated rounds 3-21, absmax 0]
        float r[8];
#pragma unroll
        for (int j = 0; j < 8; ++j) r[j] = sqr_nf(p[j]);
#pragma unroll
        for (int i = 1; i < 8; ++i)
#pragma unroll
            for (int j = 0; j < 8; ++j) r[j] += sqr_nf(p[i * 8 + j]);
        bnp[code] = ((r[0] + r[1]) + (r[2] + r[3])) + ((r[4] + r[5]) + (r[6] + r[7]));
    }
    const int cti = code >> 4, m = code & 15;
#pragma unroll
    for (int part = 0; part < 2; ++part) {
        const unsigned short* src = part ? lo : hi;
#pragma unroll
        for (int s = 0; s < 2; ++s) {
            int q = part * 2 + s;
#pragma unroll
            for (int kq = 0; kq < 4; ++kq) {
                int lane = kq * 16 + m;
                size_t off = ((size_t)(cti * 4 + q) * 64 + lane) * 8;
                *reinterpret_cast<uint4*>(wfrag + off) =
                    *reinterpret_cast<const uint4*>(src + s * 32 + kq * 8);
            }
        }
    }
}

// ---- fused main: r13-proven score structure + in-wave epilogue -------------
__global__ __launch_bounds__(256, 4) void vq_main_k(
    const float* __restrict__ X, const float* __restrict__ Wf,
    const unsigned short* __restrict__ wfrag, const float* __restrict__ bnp,
    float* __restrict__ out_q, float* __restrict__ out_idx,
    unsigned* __restrict__ hist8, float* __restrict__ lossp,
    unsigned* __restrict__ qcount, unsigned* __restrict__ queue) {
    __shared__ int idx_s[128];
    const int tid = threadIdx.x;
    const int lane = tid & 63, w = tid >> 6;
    const int m = lane & 15, kq = lane >> 4;
    const long rbase = (long)blockIdx.x * 128;
    const unsigned hstripe = (blockIdx.x & 7) * KCODES;

    // ---- score section (measured-best r13/r17 structure) -------------------
    bf16x8 ahi[2][2], alo[2][2];
#pragma unroll
    for (int rt = 0; rt < 2; ++rt) {
        long row = rbase + w * 32 + rt * 16 + m;
        const float4* xp = reinterpret_cast<const float4*>(X + row * DIM);
        cvtpair(scl(xp[kq * 2], -2.f), scl(xp[kq * 2 + 1], -2.f),
                ahi[rt][0], alo[rt][0]);
        cvtpair(scl(xp[8 + kq * 2], -2.f), scl(xp[8 + kq * 2 + 1], -2.f),
                ahi[rt][1], alo[rt][1]);
    }

    float best[2][4], sec[2][4];
    int bidx[2][4];
#pragma unroll
    for (int rt = 0; rt < 2; ++rt)
#pragma unroll
        for (int j = 0; j < 4; ++j) { best[rt][j] = 3e38f; sec[rt][j] = 3e38f; bidx[rt][j] = 0; }

    const bf16x8* fb = reinterpret_cast<const bf16x8*>(wfrag);
    bf16x8 nb0 = fb[lane], nb1 = fb[64 + lane], nb2 = fb[128 + lane], nb3 = fb[192 + lane];
    for (int cti = 0; cti < 32; ++cti) {
        bf16x8 b0 = nb0, b1 = nb1, b2 = nb2, b3 = nb3;
        if (cti < 31) {
            int nbase = (cti + 1) * 256;
            nb0 = fb[nbase + lane];       nb1 = fb[nbase + 64 + lane];
            nb2 = fb[nbase + 128 + lane]; nb3 = fb[nbase + 192 + lane];
        }
        const int kk = cti * 16 + m;
        const float wn = bnp[kk];
        f32x4 c0 = {wn, wn, wn, wn};
        f32x4 c1 = {wn, wn, wn, wn};
        c0 = __builtin_amdgcn_mfma_f32_16x16x32_bf16(ahi[0][0], b0, c0, 0, 0, 0);
        c1 = __builtin_amdgcn_mfma_f32_16x16x32_bf16(ahi[1][0], b0, c1, 0, 0, 0);
        c0 = __builtin_amdgcn_mfma_f32_16x16x32_bf16(ahi[0][1], b1, c0, 0, 0, 0);
        c1 = __builtin_amdgcn_mfma_f32_16x16x32_bf16(ahi[1][1], b1, c1, 0, 0, 0);
        c0 = __builtin_amdgcn_mfma_f32_16x16x32_bf16(alo[0][0], b0, c0, 0, 0, 0);
        c1 = __builtin_amdgcn_mfma_f32_16x16x32_bf16(alo[1][0], b0, c1, 0, 0, 0);
        c0 = __builtin_amdgcn_mfma_f32_16x16x32_bf16(alo[0][1], b1, c0, 0, 0, 0);
        c1 = __builtin_amdgcn_mfma_f32_16x16x32_bf16(alo[1][1], b1, c1, 0, 0, 0);
        c0 = __builtin_amdgcn_mfma_f32_16x16x32_bf16(ahi[0][0], b2, c0, 0, 0, 0);
        c1 = __builtin_amdgcn_mfma_f32_16x16x32_bf16(ahi[1][0], b2, c1, 0, 0, 0);
        c0 = __builtin_amdgcn_mfma_f32_16x16x32_bf16(ahi[0][1], b3, c0, 0, 0, 0);
        c1 = __builtin_amdgcn_mfma_f32_16x16x32_bf16(ahi[1][1], b3, c1, 0, 0, 0);
#pragma unroll
        for (int rt = 0; rt < 2; ++rt)
#pragma unroll
            for (int j = 0; j < 4; ++j) {
                float s = (rt == 0) ? c0[j] : c1[j];
                float nb = fminf(best[rt][j], s);
                float ns = fminf(sec[rt][j], fmaxf(best[rt][j], s));
                bidx[rt][j] = (s < best[rt][j]) ? kk : bidx[rt][j];
                best[rt][j] = nb; sec[rt][j] = ns;
            }
    }

#pragma unroll
    for (int st = 1; st < 16; st <<= 1) {
#pragma unroll
        for (int rt = 0; rt < 2; ++rt)
#pragma unroll
            for (int j = 0; j < 4; ++j) {
                float ob = __shfl_xor(best[rt][j], st);
                float os = __shfl_xor(sec[rt][j], st);
                int oi = __shfl_xor(bidx[rt][j], st);
                if (ob < best[rt][j] || (ob == best[rt][j] && oi < bidx[rt][j])) {
                    sec[rt][j] = fminf(best[rt][j], os);
                    best[rt][j] = ob; bidx[rt][j] = oi;
                } else {
                    sec[rt][j] = fminf(sec[rt][j], ob);
                }
            }
    }

    if (m == 0) {   // C/D row = kq*4 + j; publish to LDS + out_idx
#pragma unroll
        for (int rt = 0; rt < 2; ++rt)
#pragma unroll
            for (int j = 0; j < 4; ++j) {
                int r = w * 32 + rt * 16 + kq * 4 + j;
                int id = (sec[rt][j] - best[rt][j] <= MARGIN) ? -1 : bidx[rt][j];
                idx_s[r] = id;
                out_idx[rbase + r] = (float)id;   // sentinel -> refine overwrites
            }
    }
    // same-wave LDS write->read: ordered by program order + lgkmcnt (no barrier)

    // ---- fused epilogue (batched 8-deep-ILP body, per wave) ----------------
    const int g = lane >> 4, l16 = lane & 15;
    const long wbase = rbase + w * 32;
    int idxi = (lane < 32) ? idx_s[w * 32 + lane] : 0;

    if (lane < 32 && idxi < 0) {
        unsigned pos = atomicAdd(qcount, 1u);
        if (pos < QCAP) queue[pos] = (unsigned)(wbase + lane);
    }

    float4 xv[8], wv[8];
    int kk2[8];
#pragma unroll
    for (int i = 0; i < 8; ++i) {
        int r2 = g * 8 + i;
        int kf = __shfl(idxi, r2);
        kk2[i] = kf;
        xv[i] = reinterpret_cast<const float4*>(X)[(wbase + r2) * 16 + l16];
        int ksafe = (kf >= 0) ? kf : 0;
        wv[i] = reinterpret_cast<const float4*>(Wf)[(long)ksafe * 16 + l16];
    }

    float ls = 0.f;
#pragma unroll
    for (int i = 0; i < 8; ++i) {
        if (kk2[i] >= 0) {
            float4 o; float t;
            t = wv[i].x - xv[i].x; o.x = xv[i].x + t; ls = fmaf(t, t, ls);
            t = wv[i].y - xv[i].y; o.y = xv[i].y + t; ls = fmaf(t, t, ls);
            t = wv[i].z - xv[i].z; o.z = xv[i].z + t; ls = fmaf(t, t, ls);
            t = wv[i].w - xv[i].w; o.w = xv[i].w + t; ls = fmaf(t, t, ls);
            reinterpret_cast<float4*>(out_q)[(wbase + g * 8 + i) * 16 + l16] = o;
            if (l16 == 0) atomicAdd(&hist8[hstripe + kk2[i]], 1u);
        }
    }

#pragma unroll
    for (int st = 1; st < 64; st <<= 1) ls += __shfl_xor(ls, st);
    if (lane == 0 && ls != 0.f) atomicAdd(&lossp[blockIdx.x & 255], ls);
}

// ---- refine: load-balanced np-exact, W^T in LDS (validated) ----------------
#define WTP 516
__global__ __launch_bounds__(1024) void vq_refine_k(
    const float* __restrict__ X, const float* __restrict__ Wf,
    const float* __restrict__ bnp,
    float* __restrict__ out_q, float* __restrict__ out_idx,
    unsigned* __restrict__ hist8, float* __restrict__ lossp,
    const unsigned* __restrict__ qcount, const unsigned* __restrict__ queue) {
    __shared__ float WT[64 * WTP];   // WT[d][k] = W[k][d], 132KB
    const int tid = threadIdx.x;
    const int lane = tid & 63, wv = tid >> 6;

#pragma unroll
    for (int i = 0; i < 8; ++i) {
        int f = i * 1024 + tid;
        int k = f >> 4, c4 = f & 15;
        float4 v = reinterpret_cast<const float4*>(Wf)[f];
        WT[(c4 * 4 + 0) * WTP + k] = v.x;
        WT[(c4 * 4 + 1) * WTP + k] = v.y;
        WT[(c4 * 4 + 2) * WTP + k] = v.z;
        WT[(c4 * 4 + 3) * WTP + k] = v.w;
    }
    __syncthreads();

    unsigned n = *qcount;
    if (n > QCAP) n = QCAP;
    const int gwave = blockIdx.x * 16 + wv;

    float ls = 0.f;
    for (unsigned j = gwave; j < n; j += 256 * 16) {
        const long row = (long)queue[j];
        const float xv = X[row * DIM + lane];
        float sq = sqr_nf(xv);
        float rr = sq;
#pragma unroll
        for (int t2 = 1; t2 < 8; ++t2) rr += __shfl(sq, (lane & 7) + 8 * t2);
        float t01 = rr + __shfl_xor(rr, 1);
        float t03 = t01 + __shfl_xor(t01, 2);
        float Afull = t03 + __shfl_xor(t03, 4);
        const float A = __shfl(Afull, 0);
        float acc[8];
#pragma unroll
        for (int c = 0; c < 8; ++c) acc[c] = 0.f;
        for (int d = 0; d < 64; ++d) {
            float xd = __shfl(xv, d);
#pragma unroll
            for (int c = 0; c < 8; ++c)
                acc[c] = fmaf(xd, WT[d * WTP + c * 64 + lane], acc[c]);
        }
        float bs = 3e38f;
        int bi = 0;
#pragma unroll
        for (int c = 0; c < 8; ++c) {
            int k = c * 64 + lane;
            float u = A + bnp[k];
            float s2 = u - 2.0f * acc[c];
            if (s2 < bs) { bs = s2; bi = k; }
        }
#pragma unroll
        for (int st = 1; st < 64; st <<= 1) {
            float ob = __shfl_xor(bs, st);
            int oi = __shfl_xor(bi, st);
            if (ob < bs || (ob == bs && oi < bi)) { bs = ob; bi = oi; }
        }
        const int k = bi;
        if (lane == 0) {
            out_idx[row] = (float)k;
            atomicAdd(&hist8[(j & 7) * KCODES + k], 1u);
        }
        float qv = WT[lane * WTP + k];
        float diff = qv - xv;
        out_q[row * DIM + lane] = xv + diff;
        ls = fmaf(diff, diff, ls);
    }

#pragma unroll
    for (int st = 1; st < 64; st <<= 1) ls += __shfl_xor(ls, st);
    if (lane == 0 && ls != 0.f) atomicAdd(&lossp[gwave & 255], ls);
}

__global__ __launch_bounds__(512) void vq_finalize_k(
    const unsigned* __restrict__ hist8, const float* __restrict__ lossp,
    float* __restrict__ out_loss, float* __restrict__ out_perp) {
    __shared__ float red[512];
    int t = threadIdx.x;
    unsigned c = 0;
#pragma unroll
    for (int s = 0; s < 8; ++s) c += hist8[s * KCODES + t];
    float p = (float)c * (1.0f / (float)N_ROWS);
    red[t] = p * logf(p + 1e-10f);
    __syncthreads();
    for (int off = 256; off; off >>= 1) {
        if (t < off) red[t] += red[t + off];
        __syncthreads();
    }
    if (t == 0) *out_perp = expf(-red[0]);
    __syncthreads();
    red[t] = (t < 256) ? lossp[t] : 0.f;
    __syncthreads();
    for (int off = 256; off; off >>= 1) {
        if (t < off) red[t] += red[t + off];
        __syncthreads();
    }
    if (t == 0) {
        float m = red[0] / (float)(N_ROWS * DIM);
        *out_loss = m + 0.25f * m;
    }
}

extern "C" void kernel_launch(void* const* d_in, const int* in_sizes, int n_in,
                              void* d_out, int out_size, void* d_ws, size_t ws_size,
                              hipStream_t stream) {
    const float* X = (const float*)d_in[0];
    const float* Wf = (const float*)d_in[1];

    float* out = (float*)d_out;
    float* out_loss = out;
    float* out_q = out + 1;
    float* out_perp = out + 1 + (long)N_ROWS * DIM;
    float* out_idx = out + 2 + (long)N_ROWS * DIM;

    unsigned* wsu = (unsigned*)d_ws;
    float* lossp = (float*)d_ws;                    // [0..256)
    unsigned* hist8 = wsu + 256;                    // [256..4352)
    unsigned* qcount = wsu + 4352;                  // [4352]
    unsigned* queue = wsu + 4360;                   // [4360..37128)
    float* bnp = (float*)(wsu + 37128);             // [37128..37640)
    unsigned short* wfrag = (unsigned short*)(wsu + 37640);  // [37640..70408)

    hipMemsetAsync(d_ws, 0, 17424, stream);         // lossp + hist8 + qcount
    vq_wprep_k<<<2, 256, 0, stream>>>(Wf, wfrag, bnp);
    vq_main_k<<<N_ROWS / 128, 256, 0, stream>>>(X, Wf, wfrag, bnp,
                                                out_q, out_idx,
                                                hist8, lossp, qcount, queue);
    vq_refine_k<<<256, 1024, 0, stream>>>(X, Wf, bnp, out_q, out_idx,
                                          hist8, lossp, qcount, queue);
    vq_finalize_k<<<1, 512, 0, stream>>>(hist8, lossp, out_loss, out_perp);
}